// Round 6
// baseline (1557.571 us; speedup 1.0000x reference)
//
#include <hip/hip_runtime.h>
#include <stdint.h>

// ---------------- problem constants ----------------
#define N_E   8192
#define EDIM  256
#define NB    16
#define HH    32
#define WW    32
#define HW    1024            // H*W
#define NI    16384           // NB*HW (rows of zf)
#define NELEM 4194304         // NB*EDIM*HW

#define MARGIN_D1 1e-9f       // d1 rescore margin (split-MFMA key err ~1e-11)

// output flat offsets (reference return order)
#define O_ZQ   0
#define O_LOSS 4194304
#define O_DIST 4194305
#define O_IDX  4194817
#define O_ZFL  4211201
#define O_CBV  8405505
#define O_TMD  8405506

// workspace byte offsets (~25 MB; pz/pd1 live in d_out scratch regions)
#define WS_IDX   0x0        // i32 * 16384
#define WS_DMIN  0x20000    // f32 * 16384
#define WS_E2    0x40000    // f32 * 8192
#define WS_Z2    0x50000    // f32 * 16384
#define WS_MSE   0x60000    // double
#define WS_MIND  0x61000    // f32 * 8192
#define WS_ZAH   0x100000   // bf16 * 16384*256 fragment-major (8 MB)
#define WS_ZAL   0x900000   // bf16 low-residual (8 MB)
#define WS_EBH   0x1100000  // bf16 * 8192*256 fragment-major (4 MB)
#define WS_EBL   0x1500000  // bf16 low-residual (4 MB)

typedef __attribute__((ext_vector_type(8))) short bf16x8;
typedef __attribute__((ext_vector_type(4))) float f32x4;

__device__ __forceinline__ short f2bf(float f) {   // round-to-nearest-even
    unsigned u = __float_as_uint(f);
    u += 0x7fffu + ((u >> 16) & 1u);
    return (short)(u >> 16);
}
__device__ __forceinline__ float bf2f(short h) {
    return __uint_as_float(((unsigned)(unsigned short)h) << 16);
}
// monotone float->u32 key (handles negatives)
__device__ __forceinline__ unsigned keyf(float f) {
    unsigned b = __float_as_uint(f);
    return (b & 0x80000000u) ? ~b : (b | 0x80000000u);
}
__device__ __forceinline__ float unkeyf(unsigned k) {
    return (k & 0x80000000u) ? __uint_as_float(k ^ 0x80000000u) : __uint_as_float(~k);
}
// running two-smallest insert / merge on packed u64
__device__ __forceinline__ void ins2(unsigned long long& a1, unsigned long long& a2,
                                     unsigned long long v) {
    if (v < a1) { a2 = a1; a1 = v; } else if (v < a2) { a2 = v; }
}
__device__ __forceinline__ void mrg2(unsigned long long& a1, unsigned long long& a2,
                                     unsigned long long b1, unsigned long long b2) {
    unsigned long long n1 = a1 < b1 ? a1 : b1;
    unsigned long long mx = a1 < b1 ? b1 : a1;
    unsigned long long mn = a2 < b2 ? a2 : b2;
    a1 = n1; a2 = mx < mn ? mx : mn;
}

// ---------------- init ----------------
__global__ void k_init(double* __restrict__ mse) {
    if (threadIdx.x == 0) *mse = 0.0;
}

// ---------------- e2[n] = sum_c emb[n,c]^2 ----------------
__global__ void k_e2(const float* __restrict__ emb, float* __restrict__ e2) {
    int row  = blockIdx.x * 4 + (threadIdx.x >> 6);
    int lane = threadIdx.x & 63;
    float4 v = *reinterpret_cast<const float4*>(emb + (size_t)row * EDIM + lane * 4);
    float s = v.x * v.x + v.y * v.y + v.z * v.z + v.w * v.w;
    #pragma unroll
    for (int m = 32; m; m >>= 1) s += __shfl_xor(s, m);
    if (lane == 0) e2[row] = s;
}

// ---------------- z2[i] = sum_c z[b,c,h,w]^2 ----------------
__global__ void k_z2(const float* __restrict__ z, float* __restrict__ z2) {
    int i = blockIdx.x * 256 + threadIdx.x;
    int b = i >> 10, hw = i & 1023;
    const float* p = z + (size_t)b * EDIM * HW + hw;
    float s = 0.f;
    #pragma unroll 8
    for (int c = 0; c < EDIM; ++c) { float v = p[(size_t)c * HW]; s += v * v; }
    z2[i] = s;
}

// ---------------- z -> split bf16 fragment-major (hi + residual) ----------------
__global__ void k_convert_z(const float* __restrict__ z,
                            bf16x8* __restrict__ zAh, bf16x8* __restrict__ zAl) {
    __shared__ float lds[64][65];
    const int t   = threadIdx.x;
    const int hw0 = blockIdx.x * 64;
    const int c0  = blockIdx.y * 64;
    const int b   = blockIdx.z;
    #pragma unroll
    for (int cc = 0; cc < 4; ++cc) {
        const int cl = cc * 16 + (t >> 4);
        const float4 v = *reinterpret_cast<const float4*>(
            z + ((size_t)(b * 256 + c0 + cl) << 10) + hw0 + (t & 15) * 4);
        lds[cl][(t & 15) * 4 + 0] = v.x; lds[cl][(t & 15) * 4 + 1] = v.y;
        lds[cl][(t & 15) * 4 + 2] = v.z; lds[cl][(t & 15) * 4 + 3] = v.w;
    }
    __syncthreads();
    const int hl = t & 63;
    const int i  = b * 1024 + hw0 + hl;
    const int ig = i >> 4, r = i & 15;
    #pragma unroll
    for (int half = 0; half < 2; ++half) {
        const int kqi = (t >> 6) + half * 4;
        const int kq  = (c0 >> 3) + kqi;
        bf16x8 oh, ol;
        #pragma unroll
        for (int j = 0; j < 8; ++j) {
            const float f = lds[kqi * 8 + j][hl];
            const short h = f2bf(f);
            oh[j] = h;
            ol[j] = f2bf(f - bf2f(h));
        }
        zAh[(ig * 32 + kq) * 16 + r] = oh;
        zAl[(ig * 32 + kq) * 16 + r] = ol;
    }
}

// ---------------- emb -> split bf16 fragment-major ----------------
__global__ void k_convert_e(const float* __restrict__ emb,
                            bf16x8* __restrict__ eBh, bf16x8* __restrict__ eBl) {
    const int t  = threadIdx.x;
    const int kq = t & 31;
    const int n  = blockIdx.x * 8 + (t >> 5);
    const float4 u = *reinterpret_cast<const float4*>(emb + (size_t)n * EDIM + kq * 8);
    const float4 v = *reinterpret_cast<const float4*>(emb + (size_t)n * EDIM + kq * 8 + 4);
    const float fv[8] = {u.x, u.y, u.z, u.w, v.x, v.y, v.z, v.w};
    bf16x8 oh, ol;
    #pragma unroll
    for (int j = 0; j < 8; ++j) {
        const short h = f2bf(fv[j]);
        oh[j] = h;
        ol[j] = f2bf(fv[j] - bf2f(h));
    }
    eBh[((n >> 4) * 32 + kq) * 16 + (n & 15)] = oh;
    eBl[((n >> 4) * 32 + kq) * 16 + (n & 15)] = ol;
}

// ---------------- split-MFMA candidate pass (z path) ----------------
// S' = zh.eh + zh.el + zl.eh (err ~1e-9); d' = fmaf(-2,S', z2+e2).
// Per (row, 128-col group) top-2 packed (key(d'), n), flushed per ns-step.
// Pass-major MFMA: consecutive ops hit different accumulators (dep dist 8);
// per-accumulator order hh -> hl -> lh (bitwise-identical to R5).
__launch_bounds__(256, 3)
__global__ void k_cand(const bf16x8* __restrict__ zAh, const bf16x8* __restrict__ zAl,
                       const bf16x8* __restrict__ eBh, const bf16x8* __restrict__ eBl,
                       const float* __restrict__ z2, const float* __restrict__ e2,
                       unsigned long long* __restrict__ pz) {
    const int t = threadIdx.x;
    const int w = t >> 6, l = t & 63;
    const int lo16 = l & 15, hi4 = l >> 4;
    const int iblk = blockIdx.x, chunk = blockIdx.y;
    const int ig0 = (iblk * 128 + w * 32) >> 4;

    float z2r[2][4];
    #pragma unroll
    for (int ig = 0; ig < 2; ++ig)
        #pragma unroll
        for (int reg = 0; reg < 4; ++reg)
            z2r[ig][reg] = z2[iblk * 128 + w * 32 + ig * 16 + hi4 * 4 + reg];

    #pragma unroll 1
    for (int ns = 0; ns < 8; ++ns) {
        const int gcol = chunk * 64 + ns * 8;     // 16-wide col-group base
        f32x4 acc[2][8];
        #pragma unroll
        for (int ig = 0; ig < 2; ++ig)
            #pragma unroll
            for (int cg = 0; cg < 8; ++cg) acc[ig][cg] = (f32x4){0.f, 0.f, 0.f, 0.f};

        #pragma unroll
        for (int st = 0; st < 8; ++st) {
            const int arow = st * 4 + hi4;
            const bf16x8 ah0 = zAh[((ig0 + 0) * 32 + arow) * 16 + lo16];
            const bf16x8 ah1 = zAh[((ig0 + 1) * 32 + arow) * 16 + lo16];
            const bf16x8 al0 = zAl[((ig0 + 0) * 32 + arow) * 16 + lo16];
            const bf16x8 al1 = zAl[((ig0 + 1) * 32 + arow) * 16 + lo16];
            #pragma unroll
            for (int cgb = 0; cgb < 8; cgb += 4) {
                bf16x8 bh[4], bl[4];
                #pragma unroll
                for (int q = 0; q < 4; ++q) {
                    bh[q] = eBh[((gcol + cgb + q) * 32 + arow) * 16 + lo16];
                    bl[q] = eBl[((gcol + cgb + q) * 32 + arow) * 16 + lo16];
                }
                #pragma unroll
                for (int q = 0; q < 4; ++q)
                    acc[0][cgb+q] = __builtin_amdgcn_mfma_f32_16x16x32_bf16(ah0, bh[q], acc[0][cgb+q], 0, 0, 0);
                #pragma unroll
                for (int q = 0; q < 4; ++q)
                    acc[1][cgb+q] = __builtin_amdgcn_mfma_f32_16x16x32_bf16(ah1, bh[q], acc[1][cgb+q], 0, 0, 0);
                #pragma unroll
                for (int q = 0; q < 4; ++q)
                    acc[0][cgb+q] = __builtin_amdgcn_mfma_f32_16x16x32_bf16(ah0, bl[q], acc[0][cgb+q], 0, 0, 0);
                #pragma unroll
                for (int q = 0; q < 4; ++q)
                    acc[1][cgb+q] = __builtin_amdgcn_mfma_f32_16x16x32_bf16(ah1, bl[q], acc[1][cgb+q], 0, 0, 0);
                #pragma unroll
                for (int q = 0; q < 4; ++q)
                    acc[0][cgb+q] = __builtin_amdgcn_mfma_f32_16x16x32_bf16(al0, bh[q], acc[0][cgb+q], 0, 0, 0);
                #pragma unroll
                for (int q = 0; q < 4; ++q)
                    acc[1][cgb+q] = __builtin_amdgcn_mfma_f32_16x16x32_bf16(al1, bh[q], acc[1][cgb+q], 0, 0, 0);
            }
        }
        // epilogue: top-2 per (row, this 128-col group); C/D: col=lane&15,
        // row=(lane>>4)*4+reg [m89]
        float e2v[8];
        #pragma unroll
        for (int cg = 0; cg < 8; ++cg) e2v[cg] = e2[(gcol + cg) * 16 + lo16];
        #pragma unroll
        for (int ig = 0; ig < 2; ++ig) {
            #pragma unroll
            for (int reg = 0; reg < 4; ++reg) {
                unsigned long long t1 = ~0ull, t2 = ~0ull;
                #pragma unroll
                for (int cg = 0; cg < 8; ++cg) {
                    const float d = fmaf(-2.f, acc[ig][cg][reg], z2r[ig][reg] + e2v[cg]);
                    const unsigned long long pk =
                        ((unsigned long long)keyf(d) << 32) | (unsigned)((gcol + cg) * 16 + lo16);
                    ins2(t1, t2, pk);
                }
                #pragma unroll
                for (int o = 1; o < 16; o <<= 1) {
                    const unsigned long long b1 = __shfl_xor(t1, o);
                    const unsigned long long b2 = __shfl_xor(t2, o);
                    mrg2(t1, t2, b1, b2);
                }
                if (lo16 == 0) {
                    const int row = iblk * 128 + w * 32 + ig * 16 + hi4 * 4 + reg;
                    pz[((size_t)row * 64 + chunk * 8 + ns) * 2 + 0] = t1;
                    pz[((size_t)row * 64 + chunk * 8 + ns) * 2 + 1] = t2;
                }
            }
        }
    }
}

// ---------------- split-MFMA candidate pass (d1): both operands = emb ----------
// key on q = e2[m] - 2 S (e2[n] row-constant); same structure as k_cand.
__launch_bounds__(256, 3)
__global__ void k_cand_d1(const bf16x8* __restrict__ eBh, const bf16x8* __restrict__ eBl,
                          const float* __restrict__ e2,
                          unsigned long long* __restrict__ pd1) {
    const int t = threadIdx.x;
    const int w = t >> 6, l = t & 63;
    const int lo16 = l & 15, hi4 = l >> 4;
    const int iblk = blockIdx.x, chunk = blockIdx.y;
    const int ig0 = (iblk * 128 + w * 32) >> 4;

    #pragma unroll 1
    for (int ns = 0; ns < 8; ++ns) {
        const int gcol = chunk * 64 + ns * 8;     // m-range group base
        f32x4 acc[2][8];
        #pragma unroll
        for (int ig = 0; ig < 2; ++ig)
            #pragma unroll
            for (int cg = 0; cg < 8; ++cg) acc[ig][cg] = (f32x4){0.f, 0.f, 0.f, 0.f};

        #pragma unroll
        for (int st = 0; st < 8; ++st) {
            const int arow = st * 4 + hi4;
            const bf16x8 ah0 = eBh[((ig0 + 0) * 32 + arow) * 16 + lo16];
            const bf16x8 ah1 = eBh[((ig0 + 1) * 32 + arow) * 16 + lo16];
            const bf16x8 al0 = eBl[((ig0 + 0) * 32 + arow) * 16 + lo16];
            const bf16x8 al1 = eBl[((ig0 + 1) * 32 + arow) * 16 + lo16];
            #pragma unroll
            for (int cgb = 0; cgb < 8; cgb += 4) {
                bf16x8 bh[4], bl[4];
                #pragma unroll
                for (int q = 0; q < 4; ++q) {
                    bh[q] = eBh[((gcol + cgb + q) * 32 + arow) * 16 + lo16];
                    bl[q] = eBl[((gcol + cgb + q) * 32 + arow) * 16 + lo16];
                }
                #pragma unroll
                for (int q = 0; q < 4; ++q)
                    acc[0][cgb+q] = __builtin_amdgcn_mfma_f32_16x16x32_bf16(ah0, bh[q], acc[0][cgb+q], 0, 0, 0);
                #pragma unroll
                for (int q = 0; q < 4; ++q)
                    acc[1][cgb+q] = __builtin_amdgcn_mfma_f32_16x16x32_bf16(ah1, bh[q], acc[1][cgb+q], 0, 0, 0);
                #pragma unroll
                for (int q = 0; q < 4; ++q)
                    acc[0][cgb+q] = __builtin_amdgcn_mfma_f32_16x16x32_bf16(ah0, bl[q], acc[0][cgb+q], 0, 0, 0);
                #pragma unroll
                for (int q = 0; q < 4; ++q)
                    acc[1][cgb+q] = __builtin_amdgcn_mfma_f32_16x16x32_bf16(ah1, bl[q], acc[1][cgb+q], 0, 0, 0);
                #pragma unroll
                for (int q = 0; q < 4; ++q)
                    acc[0][cgb+q] = __builtin_amdgcn_mfma_f32_16x16x32_bf16(al0, bh[q], acc[0][cgb+q], 0, 0, 0);
                #pragma unroll
                for (int q = 0; q < 4; ++q)
                    acc[1][cgb+q] = __builtin_amdgcn_mfma_f32_16x16x32_bf16(al1, bh[q], acc[1][cgb+q], 0, 0, 0);
            }
        }
        float e2v[8];
        #pragma unroll
        for (int cg = 0; cg < 8; ++cg) e2v[cg] = e2[(gcol + cg) * 16 + lo16];
        #pragma unroll
        for (int ig = 0; ig < 2; ++ig) {
            #pragma unroll
            for (int reg = 0; reg < 4; ++reg) {
                unsigned long long t1 = ~0ull, t2 = ~0ull;
                #pragma unroll
                for (int cg = 0; cg < 8; ++cg) {
                    const float q = fmaf(-2.f, acc[ig][cg][reg], e2v[cg]);
                    const unsigned long long pk =
                        ((unsigned long long)keyf(q) << 32) | (unsigned)((gcol + cg) * 16 + lo16);
                    ins2(t1, t2, pk);
                }
                #pragma unroll
                for (int o = 1; o < 16; o <<= 1) {
                    const unsigned long long b1 = __shfl_xor(t1, o);
                    const unsigned long long b2 = __shfl_xor(t2, o);
                    mrg2(t1, t2, b1, b2);
                }
                if (lo16 == 0) {
                    const int row = iblk * 128 + w * 32 + ig * 16 + hi4 * 4 + reg;  // = n
                    pd1[((size_t)row * 64 + chunk * 8 + ns) * 2 + 0] = t1;
                    pd1[((size_t)row * 64 + chunk * 8 + ns) * 2 + 1] = t2;
                }
            }
        }
    }
}

// ---------------- z merge: global top-2 of 128 group entries + exact rescore ----
// 16 rows/wave, 4 lanes/row: lane (l&3) scans 32 entries; 2-step shfl merge;
// then cs=(l>>1)&1 picks candidate, hf=l&1 picks half of the exact 256-dot
// (two sequential 128-fmaf chains combined via shfl -- R3/R5-validated).
__global__ void k_zmerge(const float* __restrict__ z, const float* __restrict__ emb,
                         const float* __restrict__ z2, const float* __restrict__ e2,
                         const unsigned long long* __restrict__ pz,
                         int* __restrict__ idxi, float* __restrict__ dmin,
                         float* __restrict__ out_idx) {
    const int t = threadIdx.x, l = t & 63;
    const int row = blockIdx.x * 64 + (t >> 6) * 16 + (l >> 2);
    const int cs = (l >> 1) & 1, hf = l & 1;
    unsigned long long a1 = ~0ull, a2 = ~0ull;
    #pragma unroll 4
    for (int k = 0; k < 32; ++k)
        ins2(a1, a2, pz[(size_t)row * 128 + (l & 3) * 32 + k]);
    #pragma unroll
    for (int o = 1; o < 4; o <<= 1) {
        const unsigned long long b1 = __shfl_xor(a1, o);
        const unsigned long long b2 = __shfl_xor(a2, o);
        mrg2(a1, a2, b1, b2);
    }
    const int n = (unsigned)(cs ? a2 : a1);
    const float* zp = z + ((size_t)(row >> 10) << 18) + (row & 1023);
    const float* ep = emb + (size_t)n * EDIM;
    float acc = 0.f;
    #pragma unroll 8
    for (int c = 0; c < 128; ++c) {
        const int cc = hf * 128 + c;
        acc = fmaf(zp[(size_t)cc << 10], ep[cc], acc);
    }
    const float total = acc + __shfl_xor(acc, 1);
    const float d = fmaf(-2.f, total, z2[row] + e2[n]);
    unsigned long long pk = ((unsigned long long)__float_as_uint(d) << 32) | (unsigned)n;
    const unsigned long long op = __shfl_xor(pk, 2);
    if (op < pk) pk = op;
    if ((l & 3) == 0) {
        const int ni = (int)(pk & 0xFFFFFFFFull);
        idxi[row] = ni;
        dmin[row] = __uint_as_float((unsigned)(pk >> 32));
        out_idx[row] = (float)ni;
    }
}

// ---------------- d1 merge: wave per column, exact 2nd-smallest ----------------
__global__ void k_d1merge(const float* __restrict__ emb, const float* __restrict__ e2,
                          const unsigned long long* __restrict__ pd1,
                          float* __restrict__ mind) {
    const int t = threadIdx.x, l = t & 63;
    const int n = blockIdx.x * 4 + (t >> 6);
    const unsigned long long e0 = pd1[(size_t)n * 128 + l];
    const unsigned long long e1 = pd1[(size_t)n * 128 + 64 + l];
    unsigned long long w1 = ~0ull, w2 = ~0ull;
    ins2(w1, w2, e0); ins2(w1, w2, e1);
    #pragma unroll
    for (int o = 1; o < 64; o <<= 1) {
        const unsigned long long b1 = __shfl_xor(w1, o);
        const unsigned long long b2 = __shfl_xor(w2, o);
        mrg2(w1, w2, b1, b2);
    }
    const float thr = unkeyf((unsigned)(w2 >> 32)) + MARGIN_D1;
    const float e2n = e2[n];
    const float* np = emb + (size_t)n * EDIM;
    float b1 = 3.4e38f, b2 = 3.4e38f;
    const unsigned long long ent[2] = {e0, e1};
    #pragma unroll
    for (int s = 0; s < 2; ++s) {
        if (unkeyf((unsigned)(ent[s] >> 32)) <= thr) {
            const int m = (unsigned)ent[s];
            const float* ep = emb + (size_t)m * EDIM;
            float acc = 0.f;
            #pragma unroll 8
            for (int c = 0; c < EDIM; ++c) acc = fmaf(ep[c], np[c], acc);   // ref chain
            const float dv = (e2[m] + e2n) - 2.0f * acc;
            if (dv < b1) { b2 = b1; b1 = dv; } else if (dv < b2) { b2 = dv; }
        }
    }
    #pragma unroll
    for (int o = 1; o < 64; o <<= 1) {
        const float o1 = __shfl_xor(b1, o), o2 = __shfl_xor(b2, o);
        const float n1 = fminf(b1, o1);
        const float n2 = fminf(fmaxf(b1, o1), fminf(b2, o2));
        b1 = n1; b2 = n2;
    }
    if (l == 0) mind[n] = b2;
}

// ---------------- gather + straight-through + MSE ----------------
__global__ void k_epilogue(const float* __restrict__ z, const float* __restrict__ emb,
                           const int* __restrict__ idxi,
                           float* __restrict__ out_zq, float* __restrict__ out_zfl,
                           double* __restrict__ mse) {
    const int j4 = blockIdx.x * 256 + threadIdx.x;
    const int j  = j4 * 4;
    const int b  = j >> 18;
    const int c  = (j >> 10) & 255;
    const int hw = j & 1023;
    const int ib = (b << 10) + hw;
    const float4 zv = *reinterpret_cast<const float4*>(z + j);
    const float q0 = emb[(size_t)idxi[ib + 0] * EDIM + c];
    const float q1 = emb[(size_t)idxi[ib + 1] * EDIM + c];
    const float q2 = emb[(size_t)idxi[ib + 2] * EDIM + c];
    const float q3 = emb[(size_t)idxi[ib + 3] * EDIM + c];
    const float d0 = q0 - zv.x, d1 = q1 - zv.y, d2 = q2 - zv.z, d3 = q3 - zv.w;
    const float4 st = {zv.x + d0, zv.y + d1, zv.z + d2, zv.w + d3};  // z + (q-z)
    *reinterpret_cast<float4*>(out_zq + j) = st;
    out_zfl[j + 0] = st.x; out_zfl[j + 1] = st.y; out_zfl[j + 2] = st.z; out_zfl[j + 3] = st.w;

    double s = (double)(d0 * d0) + (double)(d1 * d1) + (double)(d2 * d2) + (double)(d3 * d3);
    #pragma unroll
    for (int m = 32; m; m >>= 1) s += __shfl_down(s, m);
    __shared__ double part[4];
    if ((threadIdx.x & 63) == 0) part[threadIdx.x >> 6] = s;
    __syncthreads();
    if (threadIdx.x == 0) atomicAdd(mse, part[0] + part[1] + part[2] + part[3]);
}

// ---------------- distances output [b,w] ----------------
__global__ void k_distances(const float* __restrict__ dmin, float* __restrict__ out_d) {
    int t = threadIdx.x;            // 512 threads
    int b = t >> 5, w = t & 31;
    float s = 0.f;
    #pragma unroll
    for (int h = 0; h < HH; ++h) {
        float d = dmin[(b << 10) + (h << 5) + w];
        s += d * d;
    }
    float mean = s * (1.0f / 32.0f);
    out_d[t] = expf(-mean / 0.02f);
}

// ---------------- finalize: tmd, cbvar, loss ----------------
__global__ void k_finalize(const float* __restrict__ mind, const double* __restrict__ mse,
                           float* __restrict__ out) {
    const int t = threadIdx.x;      // 256 threads, 1 block
    double s = 0.0, ss = 0.0;
    for (int n = t; n < N_E; n += 256) {
        const double v = (double)mind[n];
        s += v; ss += v * v;
    }
    #pragma unroll
    for (int m = 32; m; m >>= 1) { s += __shfl_down(s, m); ss += __shfl_down(ss, m); }
    __shared__ double rs[4], rss[4];
    if ((t & 63) == 0) { rs[t >> 6] = s; rss[t >> 6] = ss; }
    __syncthreads();
    if (t == 0) {
        const double S  = rs[0] + rs[1] + rs[2] + rs[3];
        const double SS = rss[0] + rss[1] + rss[2] + rss[3];
        const float tmd = (float)S;
        double var = (SS - S * S / (double)N_E) / (double)(N_E - 1);
        if (var < 0.0) var = 0.0;
        const float cbv = (float)sqrt(var);
        const float m1  = (float)(*mse / (double)NELEM);
        const float lossf = m1 + 0.25f * m1 - tmd;
        out[O_LOSS] = lossf;
        out[O_CBV]  = cbv;
        out[O_TMD]  = tmd;
    }
}

extern "C" void kernel_launch(void* const* d_in, const int* in_sizes, int n_in,
                              void* d_out, int out_size, void* d_ws, size_t ws_size,
                              hipStream_t stream) {
    const float* z   = (const float*)d_in[0];
    const float* emb = (const float*)d_in[1];
    float* out = (float*)d_out;
    char*  ws  = (char*)d_ws;

    int*      idxi = (int*)    (ws + WS_IDX);
    float*    dmin = (float*)  (ws + WS_DMIN);
    float*    e2   = (float*)  (ws + WS_E2);
    float*    z2   = (float*)  (ws + WS_Z2);
    double*   mse  = (double*) (ws + WS_MSE);
    float*    mind = (float*)  (ws + WS_MIND);
    bf16x8*   zAh  = (bf16x8*) (ws + WS_ZAH);
    bf16x8*   zAl  = (bf16x8*) (ws + WS_ZAL);
    bf16x8*   eBh  = (bf16x8*) (ws + WS_EBH);
    bf16x8*   eBl  = (bf16x8*) (ws + WS_EBL);
    // pz/pd1 live in d_out scratch: pz in the z_q region (exactly 16 MB),
    // pd1 in the z_flattened1 region (+4B for 8-alignment). Both are consumed
    // by the merge kernels BEFORE k_epilogue overwrites those regions.
    unsigned long long* pz  = (unsigned long long*)d_out;
    unsigned long long* pd1 = (unsigned long long*)((char*)d_out + (size_t)O_ZFL * 4 + 4);

    k_init     <<<1,    64,  0, stream>>>(mse);
    k_e2       <<<2048, 256, 0, stream>>>(emb, e2);
    k_z2       <<<64,   256, 0, stream>>>(z, z2);
    k_convert_z<<<dim3(16, 4, 16), 256, 0, stream>>>(z, zAh, zAl);
    k_convert_e<<<1024, 256, 0, stream>>>(emb, eBh, eBl);
    k_cand     <<<dim3(128, 8), 256, 0, stream>>>(zAh, zAl, eBh, eBl, z2, e2, pz);
    k_cand_d1  <<<dim3(64, 8),  256, 0, stream>>>(eBh, eBl, e2, pd1);
    k_zmerge   <<<256,  256, 0, stream>>>(z, emb, z2, e2, pz, idxi, dmin, out + O_IDX);
    k_d1merge  <<<2048, 256, 0, stream>>>(emb, e2, pd1, mind);
    k_epilogue <<<4096, 256, 0, stream>>>(z, emb, idxi, out + O_ZQ, out + O_ZFL, mse);
    k_distances<<<1,    512, 0, stream>>>(dmin, out + O_DIST);
    k_finalize <<<1,    256, 0, stream>>>(mind, mse, out);
}